// Round 7
// baseline (318.183 us; speedup 1.0000x reference)
//
#include <hip/hip_runtime.h>
#include <hip/hip_bf16.h>

#define D_MODEL 1024
#define NH 16
#define HD 64
#define BATCH 2
#define SEQ 2048
#define M_TOTAL (BATCH*SEQ)   // 4096

typedef _Float16 f16;
typedef _Float16 half8 __attribute__((ext_vector_type(8)));
typedef _Float16 half4v __attribute__((ext_vector_type(4)));
typedef float floatx4 __attribute__((ext_vector_type(4)));

#if __has_builtin(__builtin_amdgcn_exp2f)
#define EXP2(x) __builtin_amdgcn_exp2f(x)
#else
#define EXP2(x) __expf(0.6931471805599453f * (x))
#endif

__device__ inline void gload_lds16(const void* g, void* l) {
    __builtin_amdgcn_global_load_lds(
        (const __attribute__((address_space(1))) unsigned int*)g,
        (__attribute__((address_space(3))) unsigned int*)l, 16, 0, 0);
}

// ---------------- fp32 -> fp16 cast ----------------
__global__ void cvt_f32_f16(const float* __restrict__ src, f16* __restrict__ dst, int n4) {
    int i = blockIdx.x * blockDim.x + threadIdx.x;
    if (i < n4) {
        float4 v = ((const float4*)src)[i];
        half4v o = { (f16)v.x, (f16)v.y, (f16)v.z, (f16)v.w };
        *(half4v*)(dst + (long)i * 4) = o;
    }
}

// ---------------- m2 = mask * log2(e) in f16 (additive log2-domain mask) ----------------
__global__ void l2scale_cvt(const float* __restrict__ src, f16* __restrict__ dst, int n4) {
    int i = blockIdx.x * blockDim.x + threadIdx.x;
    if (i < n4) {
        float4 v = ((const float4*)src)[i];
        const float L2E = 1.44269504f;
        half4v o = { (f16)(v.x * L2E), (f16)(v.y * L2E), (f16)(v.z * L2E), (f16)(v.w * L2E) };
        *(half4v*)(dst + (long)i * 4) = o;
    }
}

// ---------------- fp32 [R][C] -> fp16 [C][R] transpose-cast ----------------
__global__ void transpose_cvt(const float* __restrict__ src, f16* __restrict__ dst, int R, int C) {
    __shared__ float tile[32][33];
    int tx = threadIdx.x;
    int ty = threadIdx.y;
    int c0 = blockIdx.x * 32;
    int r0 = blockIdx.y * 32;
    for (int yy = 0; yy < 32; yy += 8)
        tile[ty + yy][tx] = src[(long)(r0 + ty + yy) * C + c0 + tx];
    __syncthreads();
    for (int yy = 0; yy < 32; yy += 8)
        dst[(long)(c0 + ty + yy) * R + r0 + tx] = (f16)tile[tx][ty + yy];
}

// ---------------- 128xTN-tile fp16 MFMA GEMM, BK=64, XOR-swizzled LDS ----------------
// Single-buffered + XCD-clustered block remap (validated).
// MODE 0 (TN=128): scatter -> Qh [bh][s][d] (x0.125*log2e), Kh [bh][s][d], Vtg [bh][d][s]
// MODE 1 (TN=64):  out[m][n] = acc + bias (fp32)
template<int MODE, int TN>
__global__ __launch_bounds__(256) void gemm_mfma(
    const f16* __restrict__ A, const f16* __restrict__ BT,
    const float* __restrict__ bias,
    f16* __restrict__ Qh, f16* __restrict__ Kh, f16* __restrict__ Vtg,
    float* __restrict__ out, int Kdim)
{
    constexpr int NF = TN / 32;          // n-frags per wave
    __shared__ f16 Ah[128 * 64];
    __shared__ f16 Bh[TN * 64];
    int tid  = threadIdx.x;
    int wid  = tid >> 6;
    int lane = tid & 63;
    int quad = lane >> 4;
    int l16  = lane & 15;

    // XCD-clustered bijective remap (validated: halved attn FETCH in R5)
    int id  = blockIdx.y * gridDim.x + blockIdx.x;
    int xcd = id & 7;
    int s   = id >> 3;
    constexpr int CN = (MODE == 0) ? 12 : 8;
    int n0 = ((xcd & 1) * CN + s % CN) * TN;
    int m0 = ((xcd >> 1) * 8 + s / CN) * 128;

    int mrow = (wid >> 1) * 64;
    int ncol = (wid & 1) * (TN / 2);
    int grow = lane >> 3;                 // 0..7
    int gchunk = (lane & 7) ^ (grow & 7); // swizzled source chunk
    int sw0 = ((quad)     ^ (l16 & 7)) * 8;   // k-half 0
    int sw1 = ((quad + 4) ^ (l16 & 7)) * 8;   // k-half 1

    floatx4 acc[4][NF];
    #pragma unroll
    for (int mb = 0; mb < 4; mb++)
        #pragma unroll
        for (int nb = 0; nb < NF; nb++) acc[mb][nb] = (floatx4){0.f, 0.f, 0.f, 0.f};

    const f16* Abase = A + (long)m0 * Kdim;
    const f16* Bbase = BT + (long)n0 * Kdim;

    for (int k0 = 0; k0 < Kdim; k0 += 64) {
        #pragma unroll
        for (int j = 0; j < 4; j++) {
            int r = j * 32 + wid * 8 + grow;
            gload_lds16(Abase + (long)r * Kdim + k0 + gchunk * 8, &Ah[(j * 32 + wid * 8) * 64]);
        }
        #pragma unroll
        for (int j = 0; j < TN / 32; j++) {
            int r = j * 32 + wid * 8 + grow;
            gload_lds16(Bbase + (long)r * Kdim + k0 + gchunk * 8, &Bh[(j * 32 + wid * 8) * 64]);
        }
        __syncthreads();
        #pragma unroll
        for (int h = 0; h < 2; h++) {
            int sw = h ? sw1 : sw0;
            half8 af[4];
            #pragma unroll
            for (int mb = 0; mb < 4; mb++)
                af[mb] = *(const half8*)&Ah[(mrow + mb * 16 + l16) * 64 + sw];
            #pragma unroll
            for (int nb = 0; nb < NF; nb++) {
                half8 bf = *(const half8*)&Bh[(ncol + nb * 16 + l16) * 64 + sw];
                #pragma unroll
                for (int mb = 0; mb < 4; mb++)
                    acc[mb][nb] = __builtin_amdgcn_mfma_f32_16x16x32_f16(af[mb], bf, acc[mb][nb], 0, 0, 0);
            }
        }
        __syncthreads();
    }

    #pragma unroll
    for (int nb = 0; nb < NF; nb++) {
        int n = n0 + ncol + nb * 16 + l16;
        float bv = bias[n];
        int head = 0, t = 0, d = 0;
        if (MODE == 0) { head = n / 192; int rem = n % 192; t = rem / 64; d = rem % 64; }
        #pragma unroll
        for (int mb = 0; mb < 4; mb++) {
            int mbase = m0 + mrow + mb * 16 + quad * 4;
            if (MODE == 0) {
                int b = mbase >> 11;
                int ss = mbase & 2047;
                long bh = b * NH + head;
                if (t == 2) {
                    half4v pack;
                    #pragma unroll
                    for (int r = 0; r < 4; r++) pack[r] = (f16)(acc[mb][nb][r] + bv);
                    *(half4v*)&Vtg[(bh * HD + d) * SEQ + ss] = pack;
                } else if (t == 0) {
                    // 0.125 (1/sqrt(64)) * log2(e): QK^T lands directly in log2 domain
                    #pragma unroll
                    for (int r = 0; r < 4; r++)
                        Qh[(bh * SEQ + ss + r) * HD + d] = (f16)((acc[mb][nb][r] + bv) * 0.18033688f);
                } else {
                    #pragma unroll
                    for (int r = 0; r < 4; r++)
                        Kh[(bh * SEQ + ss + r) * HD + d] = (f16)(acc[mb][nb][r] + bv);
                }
            } else {
                #pragma unroll
                for (int r = 0; r < 4; r++)
                    out[(long)(mbase + r) * D_MODEL + n] = acc[mb][nb][r] + bv;
            }
        }
    }
}

// ---------------- flash attention v7: 4 q-groups x 2 k-groups, 32q/wave ---------------
// grid (16, 32) = 512 blocks, 512 threads = 8 waves. Wave (qg = wid&3, kg = wid>>2)
// owns 32 q-rows and every other k-tile (k0 = (2t+kg)*64). Per iteration the block
// stages FOUR tiles (K/V for two consecutive k-steps); each wave reads only its kg's
// tiles -> per-CU LDS frag traffic matches the 32q floor (~43us) while keeping
// 16 waves/CU (R6 had the floor but only 8 waves/CU -> latency-bound at 72us).
// Partial O/ssum combined across kg pairs through LDS at the end.
// Keeps: XCD-clustered remap, log2-domain softmax, ones-MFMA denominators, E prefetch.
// Dynamic LDS: 4 tiles (32KB) + Pl 8x32x68 f16 (34.8KB) = 67584 B -> 2 blocks/CU.
__global__ __launch_bounds__(512, 4) void attn(
    const f16* __restrict__ Qh, const f16* __restrict__ Kh, const f16* __restrict__ Vtg,
    const f16* __restrict__ E, f16* __restrict__ valh)
{
    extern __shared__ f16 sm[];
    f16* Kt0 = sm;            // [64*64] keys (2t)*64
    f16* Kt1 = sm + 4096;     // keys (2t+1)*64
    f16* Vt0 = sm + 8192;
    f16* Vt1 = sm + 12288;
    f16* Plb = sm + 16384;    // [8][32*68]
    int tid  = threadIdx.x;
    int wid  = tid >> 6;             // 0..7
    int lane = tid & 63;
    int quad = lane >> 4;
    int l16  = lane & 15;
    int qg = wid & 3;
    int kg = wid >> 2;

    int id   = blockIdx.y * 16 + blockIdx.x;   // linear dispatch id
    int xcd  = id & 7;
    int slot = id >> 3;
    int bh   = ((xcd & 3) << 3) | (slot >> 3);
    int qx   = ((xcd >> 2) << 3) | (slot & 7);
    int b  = bh >> 4;
    int h  = bh & 15;
    int qblk = qx * 128;
    int q0 = qblk + qg * 32;

    int grow = lane >> 3;                     // 0..7
    int gchunk = (lane & 7) ^ (grow & 7);
    int sw0 = ((quad)     ^ (l16 & 7)) * 8;   // k-half 0
    int sw1 = ((quad + 4) ^ (l16 & 7)) * 8;   // k-half 1

    const f16* Qbase = Qh + ((long)bh * SEQ + q0) * HD;
    half8 qf[2][2];
    #pragma unroll
    for (int m = 0; m < 2; m++)
        #pragma unroll
        for (int c = 0; c < 2; c++)
            qf[m][c] = *(const half8*)&Qbase[(long)(m * 16 + l16) * HD + c * 32 + quad * 8];

    half8 onesv;
    #pragma unroll
    for (int j = 0; j < 8; j++) onesv[j] = (f16)1.0f;

    floatx4 Of[2][4];
    floatx4 ssum[2];
    #pragma unroll
    for (int m = 0; m < 2; m++) {
        ssum[m] = (floatx4){0.f, 0.f, 0.f, 0.f};
        #pragma unroll
        for (int nb = 0; nb < 4; nb++) Of[m][nb] = (floatx4){0.f, 0.f, 0.f, 0.f};
    }

    const f16* Kb = Kh + (long)bh * SEQ * HD;
    const f16* Vb = Vtg + (long)bh * HD * SEQ;
    const f16* Eb = E + (long)qblk * SEQ;

    // staging: wave w covers tile (w>>1), rows (w&1)*32..+31 (4 gload calls of 8 rows)
    int stile = wid >> 1;            // 0: K-even, 1: K-odd, 2: V-even, 3: V-odd
    f16* sdst = (stile == 0) ? Kt0 : (stile == 1) ? Kt1 : (stile == 2) ? Vt0 : Vt1;
    bool sK = (stile < 2);
    int skodd = stile & 1;

    f16* Kt = kg ? Kt1 : Kt0;
    f16* Vt = kg ? Vt1 : Vt0;
    f16* Pl = Plb + wid * (32 * 68);

    for (int t = 0; t < 16; ++t) {
        if (t) __syncthreads();      // prior compute's tile reads done
        {
            int kk = (2 * t + skodd) * 64;
            #pragma unroll
            for (int j = 0; j < 4; j++) {
                int r = (wid & 1) * 32 + j * 8 + grow;
                const f16* src = sK ? (Kb + (long)(kk + r) * HD + gchunk * 8)
                                    : (Vb + (long)r * SEQ + kk + gchunk * 8);
                gload_lds16(src, &sdst[((wid & 1) * 32 + j * 8) * 64]);
            }
        }
        __syncthreads();             // vmcnt(0) drain: all 4 tiles visible

        int k0 = (2 * t + kg) * 64;

        // m2 loads: issue before QK so L2 latency hides under MFMAs
        f16 ef[2][4][4];
        #pragma unroll
        for (int m = 0; m < 2; m++)
            #pragma unroll
            for (int r = 0; r < 4; r++) {
                const f16* Erow = Eb + (long)(qg * 32 + m * 16 + quad * 4 + r) * SEQ + k0 + l16;
                #pragma unroll
                for (int kb = 0; kb < 4; kb++) ef[m][r][kb] = Erow[kb * 16];
            }

        // QK^T: 32 q-rows x 64 keys (result already in log2 domain)
        floatx4 sc[2][4];
        __builtin_amdgcn_s_setprio(1);
        #pragma unroll
        for (int kb = 0; kb < 4; kb++) {
            half8 kf0 = *(const half8*)&Kt[(kb * 16 + l16) * 64 + sw0];
            half8 kf1 = *(const half8*)&Kt[(kb * 16 + l16) * 64 + sw1];
            #pragma unroll
            for (int m = 0; m < 2; m++) {
                floatx4 sacc = (floatx4){0.f, 0.f, 0.f, 0.f};
                sacc = __builtin_amdgcn_mfma_f32_16x16x32_f16(qf[m][0], kf0, sacc, 0, 0, 0);
                sacc = __builtin_amdgcn_mfma_f32_16x16x32_f16(qf[m][1], kf1, sacc, 0, 0, 0);
                sc[m][kb] = sacc;
            }
        }
        __builtin_amdgcn_s_setprio(0);

        // p = exp2(s + m2)
        #pragma unroll
        for (int m = 0; m < 2; m++)
            #pragma unroll
            for (int kb = 0; kb < 4; kb++)
                #pragma unroll
                for (int r = 0; r < 4; r++) {
                    float p = EXP2(sc[m][kb][r] + (float)ef[m][r][kb]);
                    Pl[(m * 16 + quad * 4 + r) * 68 + kb * 16 + l16] = (f16)p;
                }

        // wave-private LDS round-trip (C-layout -> A-layout); no barrier needed
        half8 pf[2][2];
        #pragma unroll
        for (int m = 0; m < 2; m++)
            #pragma unroll
            for (int c = 0; c < 2; c++)
                pf[m][c] = *(const half8*)&Pl[(m * 16 + l16) * 68 + c * 32 + quad * 8];

        __builtin_amdgcn_s_setprio(1);
        // denominators: sums[q] += sum_key P[q][key] via ones-B MFMA
        #pragma unroll
        for (int m = 0; m < 2; m++) {
            ssum[m] = __builtin_amdgcn_mfma_f32_16x16x32_f16(pf[m][0], onesv, ssum[m], 0, 0, 0);
            ssum[m] = __builtin_amdgcn_mfma_f32_16x16x32_f16(pf[m][1], onesv, ssum[m], 0, 0, 0);
        }
        #pragma unroll
        for (int nb = 0; nb < 4; nb++) {
            half8 vf0 = *(const half8*)&Vt[(nb * 16 + l16) * 64 + sw0];
            half8 vf1 = *(const half8*)&Vt[(nb * 16 + l16) * 64 + sw1];
            #pragma unroll
            for (int m = 0; m < 2; m++) {
                Of[m][nb] = __builtin_amdgcn_mfma_f32_16x16x32_f16(pf[m][0], vf0, Of[m][nb], 0, 0, 0);
                Of[m][nb] = __builtin_amdgcn_mfma_f32_16x16x32_f16(pf[m][1], vf1, Of[m][nb], 0, 0, 0);
            }
        }
        __builtin_amdgcn_s_setprio(0);
    }

    // ---- cross-kg combine (through LDS, reusing tile+Pl space) ----
    __syncthreads();
    float* xch = (float*)sm;                 // 48 f32/lane stride, 16B-aligned slots
    float* p = xch + (long)(qg * 64 + lane) * 48;
    if (kg == 1) {
        #pragma unroll
        for (int m = 0; m < 2; m++)
            #pragma unroll
            for (int nb = 0; nb < 4; nb++)
                *(floatx4*)(p + (m * 4 + nb) * 4) = Of[m][nb];
        *(floatx4*)(p + 32) = ssum[0];
        *(floatx4*)(p + 40) = ssum[1];
    }
    __syncthreads();
    if (kg == 0) {
        #pragma unroll
        for (int m = 0; m < 2; m++) {
            #pragma unroll
            for (int nb = 0; nb < 4; nb++)
                Of[m][nb] += *(const floatx4*)(p + (m * 4 + nb) * 4);
            ssum[m] += *(const floatx4*)(p + 32 + m * 8);
        }
        float rinv[2][4];
        #pragma unroll
        for (int m = 0; m < 2; m++)
            #pragma unroll
            for (int r = 0; r < 4; r++) rinv[m][r] = 1.f / ssum[m][r];

        #pragma unroll
        for (int m = 0; m < 2; m++)
            #pragma unroll
            for (int nb = 0; nb < 4; nb++)
                #pragma unroll
                for (int r = 0; r < 4; r++) {
                    int q = q0 + m * 16 + quad * 4 + r;
                    int d = nb * 16 + l16;
                    valh[((long)(b * SEQ + q)) * D_MODEL + h * HD + d] = (f16)(Of[m][nb][r] * rinv[m][r]);
                }
    }
}

extern "C" void kernel_launch(void* const* d_in, const int* in_sizes, int n_in,
                              void* d_out, int out_size, void* d_ws, size_t ws_size,
                              hipStream_t stream) {
    const float* x    = (const float*)d_in[0];
    const float* mask = (const float*)d_in[1];
    const float* Wqkv = (const float*)d_in[2];
    const float* bqkv = (const float*)d_in[3];
    const float* Wout = (const float*)d_in[4];
    const float* bout = (const float*)d_in[5];
    float* out = (float*)d_out;

    char* ws = (char*)d_ws;
    f16* xh    = (f16*)(ws + 0);          // 8 MB: [4096][1024]; dead after gemm0
    f16* E     = (f16*)(ws + 0);          // 8 MB: [2048][2048] mask*log2e — overlays xh
    f16* WqkvT = (f16*)(ws + 8388608);    // 6 MB: [3072][1024]
    f16* WoutT = (f16*)(ws + 14680064);   // 2 MB: [1024][1024]
    f16* Qh    = (f16*)(ws + 16777216);   // 8 MB: [32][2048][64] (pre-scaled 0.125*log2e)
    f16* Kh    = (f16*)(ws + 25165824);   // 8 MB: [32][2048][64]
    f16* Vtg   = (f16*)(ws + 33554432);   // 8 MB: [32][64][2048] (V transposed)
    f16* valh  = (f16*)(ws + 41943040);   // 8 MB: [4096][1024]

    cvt_f32_f16<<<4096, 256, 0, stream>>>(x, xh, M_TOTAL * D_MODEL / 4);
    transpose_cvt<<<dim3(96, 32), dim3(32, 8), 0, stream>>>(Wqkv, WqkvT, 1024, 3072);
    transpose_cvt<<<dim3(32, 32), dim3(32, 8), 0, stream>>>(Wout, WoutT, 1024, 1024);
    gemm_mfma<0, 128><<<dim3(24, 32), 256, 0, stream>>>(xh, WqkvT, bqkv, Qh, Kh, Vtg, nullptr, 1024);
    l2scale_cvt<<<4096, 256, 0, stream>>>(mask, E, SEQ * SEQ / 4);   // xh dead now
    attn<<<dim3(16, 32), 512, 67584, stream>>>(Qh, Kh, Vtg, E, valh);
    gemm_mfma<1, 64><<<dim3(16, 32), 256, 0, stream>>>(valh, WoutT, bout, nullptr, nullptr, nullptr, out, 1024);
}

// Round 8
// 222.926 us; speedup vs baseline: 1.4273x; 1.4273x over previous
//
#include <hip/hip_runtime.h>
#include <hip/hip_bf16.h>

#define D_MODEL 1024
#define NH 16
#define HD 64
#define BATCH 2
#define SEQ 2048
#define M_TOTAL (BATCH*SEQ)   // 4096

typedef _Float16 f16;
typedef _Float16 half8 __attribute__((ext_vector_type(8)));
typedef _Float16 half4v __attribute__((ext_vector_type(4)));
typedef float floatx4 __attribute__((ext_vector_type(4)));

#if __has_builtin(__builtin_amdgcn_exp2f)
#define EXP2(x) __builtin_amdgcn_exp2f(x)
#else
#define EXP2(x) __expf(0.6931471805599453f * (x))
#endif

__device__ inline void gload_lds16(const void* g, void* l) {
    __builtin_amdgcn_global_load_lds(
        (const __attribute__((address_space(1))) unsigned int*)g,
        (__attribute__((address_space(3))) unsigned int*)l, 16, 0, 0);
}

// ---------------- fp32 -> fp16 cast ----------------
__global__ void cvt_f32_f16(const float* __restrict__ src, f16* __restrict__ dst, int n4) {
    int i = blockIdx.x * blockDim.x + threadIdx.x;
    if (i < n4) {
        float4 v = ((const float4*)src)[i];
        half4v o = { (f16)v.x, (f16)v.y, (f16)v.z, (f16)v.w };
        *(half4v*)(dst + (long)i * 4) = o;
    }
}

// ---------------- m2 = mask * log2(e) in f16 (additive log2-domain mask) ----------------
__global__ void l2scale_cvt(const float* __restrict__ src, f16* __restrict__ dst, int n4) {
    int i = blockIdx.x * blockDim.x + threadIdx.x;
    if (i < n4) {
        float4 v = ((const float4*)src)[i];
        const float L2E = 1.44269504f;
        half4v o = { (f16)(v.x * L2E), (f16)(v.y * L2E), (f16)(v.z * L2E), (f16)(v.w * L2E) };
        *(half4v*)(dst + (long)i * 4) = o;
    }
}

// ---------------- fp32 [R][C] -> fp16 [C][R] transpose-cast ----------------
__global__ void transpose_cvt(const float* __restrict__ src, f16* __restrict__ dst, int R, int C) {
    __shared__ float tile[32][33];
    int tx = threadIdx.x;
    int ty = threadIdx.y;
    int c0 = blockIdx.x * 32;
    int r0 = blockIdx.y * 32;
    for (int yy = 0; yy < 32; yy += 8)
        tile[ty + yy][tx] = src[(long)(r0 + ty + yy) * C + c0 + tx];
    __syncthreads();
    for (int yy = 0; yy < 32; yy += 8)
        dst[(long)(c0 + ty + yy) * R + r0 + tx] = (f16)tile[tx][ty + yy];
}

// ---------------- 128xTN-tile fp16 MFMA GEMM, BK=64, XOR-swizzled LDS ----------------
// R1-verified version: single-buffered, linear block mapping (50us @ 61% MfmaUtil).
// MODE 0 (TN=128): scatter -> Qh [bh][s][d] (x0.125*log2e), Kh [bh][s][d], Vtg [bh][d][s]
// MODE 1 (TN=64):  out[m][n] = acc + bias (fp32)
template<int MODE, int TN>
__global__ __launch_bounds__(256) void gemm_mfma(
    const f16* __restrict__ A, const f16* __restrict__ BT,
    const float* __restrict__ bias,
    f16* __restrict__ Qh, f16* __restrict__ Kh, f16* __restrict__ Vtg,
    float* __restrict__ out, int Kdim)
{
    constexpr int NF = TN / 32;          // n-frags per wave
    __shared__ f16 Ah[128 * 64];
    __shared__ f16 Bh[TN * 64];
    int tid  = threadIdx.x;
    int wid  = tid >> 6;
    int lane = tid & 63;
    int quad = lane >> 4;
    int l16  = lane & 15;
    int m0 = blockIdx.y * 128;
    int n0 = blockIdx.x * TN;
    int mrow = (wid >> 1) * 64;
    int ncol = (wid & 1) * (TN / 2);
    // staging: lane -> row (lane>>3) within 8-row group, global chunk (lane&7)^(row&7)
    int grow = lane >> 3;                 // 0..7
    int gchunk = (lane & 7) ^ (grow & 7); // swizzled source chunk
    // frag-read swizzled chunk offsets (f16 units), lane-constant
    int sw0 = ((quad)     ^ (l16 & 7)) * 8;   // k-half 0
    int sw1 = ((quad + 4) ^ (l16 & 7)) * 8;   // k-half 1

    floatx4 acc[4][NF];
    #pragma unroll
    for (int mb = 0; mb < 4; mb++)
        #pragma unroll
        for (int nb = 0; nb < NF; nb++) acc[mb][nb] = (floatx4){0.f, 0.f, 0.f, 0.f};

    const f16* Abase = A + (long)m0 * Kdim;
    const f16* Bbase = BT + (long)n0 * Kdim;

    for (int k0 = 0; k0 < Kdim; k0 += 64) {
        #pragma unroll
        for (int j = 0; j < 4; j++) {
            int r = j * 32 + wid * 8 + grow;
            gload_lds16(Abase + (long)r * Kdim + k0 + gchunk * 8, &Ah[(j * 32 + wid * 8) * 64]);
        }
        #pragma unroll
        for (int j = 0; j < TN / 32; j++) {
            int r = j * 32 + wid * 8 + grow;
            gload_lds16(Bbase + (long)r * Kdim + k0 + gchunk * 8, &Bh[(j * 32 + wid * 8) * 64]);
        }
        __syncthreads();
        #pragma unroll
        for (int h = 0; h < 2; h++) {
            int sw = h ? sw1 : sw0;
            half8 af[4];
            #pragma unroll
            for (int mb = 0; mb < 4; mb++)
                af[mb] = *(const half8*)&Ah[(mrow + mb * 16 + l16) * 64 + sw];
            #pragma unroll
            for (int nb = 0; nb < NF; nb++) {
                half8 bf = *(const half8*)&Bh[(ncol + nb * 16 + l16) * 64 + sw];
                #pragma unroll
                for (int mb = 0; mb < 4; mb++)
                    acc[mb][nb] = __builtin_amdgcn_mfma_f32_16x16x32_f16(af[mb], bf, acc[mb][nb], 0, 0, 0);
            }
        }
        __syncthreads();
    }

    #pragma unroll
    for (int nb = 0; nb < NF; nb++) {
        int n = n0 + ncol + nb * 16 + l16;
        float bv = bias[n];
        int head = 0, t = 0, d = 0;
        if (MODE == 0) { head = n / 192; int rem = n % 192; t = rem / 64; d = rem % 64; }
        #pragma unroll
        for (int mb = 0; mb < 4; mb++) {
            int mbase = m0 + mrow + mb * 16 + quad * 4;
            if (MODE == 0) {
                int b = mbase >> 11;
                int s = mbase & 2047;
                long bh = b * NH + head;
                if (t == 2) {
                    half4v pack;
                    #pragma unroll
                    for (int r = 0; r < 4; r++) pack[r] = (f16)(acc[mb][nb][r] + bv);
                    *(half4v*)&Vtg[(bh * HD + d) * SEQ + s] = pack;
                } else if (t == 0) {
                    // 0.125 (1/sqrt(64)) * log2(e): QK^T lands directly in log2 domain
                    #pragma unroll
                    for (int r = 0; r < 4; r++)
                        Qh[(bh * SEQ + s + r) * HD + d] = (f16)((acc[mb][nb][r] + bv) * 0.18033688f);
                } else {
                    #pragma unroll
                    for (int r = 0; r < 4; r++)
                        Kh[(bh * SEQ + s + r) * HD + d] = (f16)(acc[mb][nb][r] + bv);
                }
            } else {
                #pragma unroll
                for (int r = 0; r < 4; r++)
                    out[(long)(mbase + r) * D_MODEL + n] = acc[mb][nb][r] + bv;
            }
        }
    }
}

// ---------------- flash attention v8: R1's v2 structure + validated deltas ----------------
// grid (16, 32) = 512 blocks, 512 threads, 8 waves x 16 q-rows.
// Structure = R1 (best total 195us): K/V/E single-buffered DMA staging, 2 barriers/tile.
// Deltas (validated, orthogonal):
//  - XCD bijective remap of (bh, q-panel)  [R5: FETCH 74->37 MB]
//  - log2-domain softmax: p = exp2(s + m2), Q pre-scaled 0.125*log2e  [VALU -2 ops/elem]
//  - denominators via ones-MFMA (2/iter) instead of 16 VALU adds + end shuffle-reduce
//  - s_setprio(1) around MFMA clusters
__global__ __launch_bounds__(512) void attn(
    const f16* __restrict__ Qh, const f16* __restrict__ Kh, const f16* __restrict__ Vtg,
    const f16* __restrict__ E, f16* __restrict__ valh)
{
    __shared__ f16 Kl[64 * 64];      // [key][d]
    __shared__ f16 Vt[64 * 64];      // [d][key]
    __shared__ f16 El[128 * 64];     // [q][key] tile of mask*log2e
    __shared__ f16 Pl[8][16 * 68];   // per-wave P [q][key], stride 68 (write-conflict-free)
    int tid  = threadIdx.x;
    int wid  = tid >> 6;             // 0..7
    int lane = tid & 63;
    int quad = lane >> 4;
    int l16  = lane & 15;

    // XCD-clustered bijective remap: each XCD sees 8 bh x 8 q-panels -> L2-resident K/V+E
    int id   = blockIdx.y * 16 + blockIdx.x;
    int xcd  = id & 7;
    int slot = id >> 3;
    int bh   = ((xcd & 3) << 3) | (slot >> 3);
    int qx   = ((xcd >> 2) << 3) | (slot & 7);
    int b  = bh >> 4;
    int h  = bh & 15;
    int qblk = qx * 128;
    int q0 = qblk + wid * 16;

    // staging: lane -> row wid*8 + (lane>>3); LDS chunk lane&7 <- global chunk (lane&7)^(row&7)
    int wrow = wid * 8 + (lane >> 3);         // 0..63
    int kchunk = (lane & 7) ^ (wrow & 7);
    // frag-read swizzled chunk offsets (f16 units), lane-constant
    int sw0 = ((quad)     ^ (l16 & 7)) * 8;   // k-half 0
    int sw1 = ((quad + 4) ^ (l16 & 7)) * 8;   // k-half 1

    const f16* Qbase = Qh + ((long)bh * SEQ + q0) * HD;
    half8 qf[2];
    #pragma unroll
    for (int c = 0; c < 2; c++)
        qf[c] = *(const half8*)&Qbase[(long)l16 * HD + c * 32 + quad * 8];

    half8 onesv;
    #pragma unroll
    for (int j = 0; j < 8; j++) onesv[j] = (f16)1.0f;

    floatx4 Of[4];
    floatx4 ssum = (floatx4){0.f, 0.f, 0.f, 0.f};
    #pragma unroll
    for (int nb = 0; nb < 4; nb++) Of[nb] = (floatx4){0.f, 0.f, 0.f, 0.f};

    const f16* Kb = Kh + (long)bh * SEQ * HD;
    const f16* Vb = Vtg + (long)bh * HD * SEQ;
    const f16* Eb = E + (long)qblk * SEQ;

    for (int k0 = 0; k0 < SEQ; k0 += 64) {
        __syncthreads();
        // K: rows = keys, V: rows = d, E: rows = local q (128 rows -> two calls)
        gload_lds16(Kb + (long)(k0 + wrow) * HD + kchunk * 8, &Kl[(wid * 8) * 64]);
        gload_lds16(Vb + (long)wrow * SEQ + k0 + kchunk * 8, &Vt[(wid * 8) * 64]);
        gload_lds16(Eb + (long)wrow * SEQ + k0 + kchunk * 8, &El[(wid * 8) * 64]);
        gload_lds16(Eb + (long)(64 + wrow) * SEQ + k0 + kchunk * 8, &El[(64 + wid * 8) * 64]);
        __syncthreads();

        // QK^T: 16 q-rows x 64 keys (result already in log2 domain)
        floatx4 sc[4];
        __builtin_amdgcn_s_setprio(1);
        #pragma unroll
        for (int kb = 0; kb < 4; kb++) {
            half8 kf0 = *(const half8*)&Kl[(kb * 16 + l16) * 64 + sw0];
            half8 kf1 = *(const half8*)&Kl[(kb * 16 + l16) * 64 + sw1];
            floatx4 s = (floatx4){0.f, 0.f, 0.f, 0.f};
            s = __builtin_amdgcn_mfma_f32_16x16x32_f16(qf[0], kf0, s, 0, 0, 0);
            s = __builtin_amdgcn_mfma_f32_16x16x32_f16(qf[1], kf1, s, 0, 0, 0);
            sc[kb] = s;
        }
        __builtin_amdgcn_s_setprio(0);

        // p = exp2(s + m2); m2 read from swizzled LDS (2-way conflicts only)
        int lrow = wid * 16 + quad * 4;
        #pragma unroll
        for (int kb = 0; kb < 4; kb++) {
            int cchunk = kb * 2 + (l16 >> 3);
            #pragma unroll
            for (int r = 0; r < 4; r++) {
                int lr = lrow + r;
                f16 ev = El[lr * 64 + ((cchunk ^ (lr & 7)) * 8) + (l16 & 7)];
                float p = EXP2(sc[kb][r] + (float)ev);
                Pl[wid][(quad * 4 + r) * 68 + kb * 16 + l16] = (f16)p;
            }
        }

        // wave-private LDS round-trip (C-layout -> A-layout); no barrier needed
        half8 pf0 = *(const half8*)&Pl[wid][l16 * 68 + quad * 8];
        half8 pf1 = *(const half8*)&Pl[wid][l16 * 68 + 32 + quad * 8];

        __builtin_amdgcn_s_setprio(1);
        // denominators: ssum[q] += sum_key P[q][key] via ones-B MFMA
        ssum = __builtin_amdgcn_mfma_f32_16x16x32_f16(pf0, onesv, ssum, 0, 0, 0);
        ssum = __builtin_amdgcn_mfma_f32_16x16x32_f16(pf1, onesv, ssum, 0, 0, 0);
        #pragma unroll
        for (int nb = 0; nb < 4; nb++) {
            half8 vf0 = *(const half8*)&Vt[(nb * 16 + l16) * 64 + sw0];
            half8 vf1 = *(const half8*)&Vt[(nb * 16 + l16) * 64 + sw1];
            Of[nb] = __builtin_amdgcn_mfma_f32_16x16x32_f16(pf0, vf0, Of[nb], 0, 0, 0);
            Of[nb] = __builtin_amdgcn_mfma_f32_16x16x32_f16(pf1, vf1, Of[nb], 0, 0, 0);
        }
        __builtin_amdgcn_s_setprio(0);
    }

    float rinv[4];
    #pragma unroll
    for (int r = 0; r < 4; r++) rinv[r] = 1.f / ssum[r];

    #pragma unroll
    for (int nb = 0; nb < 4; nb++)
        #pragma unroll
        for (int r = 0; r < 4; r++) {
            int q = q0 + quad * 4 + r;
            int d = nb * 16 + l16;
            valh[((long)(b * SEQ + q)) * D_MODEL + h * HD + d] = (f16)(Of[nb][r] * rinv[r]);
        }
}

extern "C" void kernel_launch(void* const* d_in, const int* in_sizes, int n_in,
                              void* d_out, int out_size, void* d_ws, size_t ws_size,
                              hipStream_t stream) {
    const float* x    = (const float*)d_in[0];
    const float* mask = (const float*)d_in[1];
    const float* Wqkv = (const float*)d_in[2];
    const float* bqkv = (const float*)d_in[3];
    const float* Wout = (const float*)d_in[4];
    const float* bout = (const float*)d_in[5];
    float* out = (float*)d_out;

    char* ws = (char*)d_ws;
    f16* xh    = (f16*)(ws + 0);          // 8 MB: [4096][1024]; dead after gemm0
    f16* E     = (f16*)(ws + 0);          // 8 MB: [2048][2048] mask*log2e — overlays xh
    f16* WqkvT = (f16*)(ws + 8388608);    // 6 MB: [3072][1024]
    f16* WoutT = (f16*)(ws + 14680064);   // 2 MB: [1024][1024]
    f16* Qh    = (f16*)(ws + 16777216);   // 8 MB: [32][2048][64] (pre-scaled 0.125*log2e)
    f16* Kh    = (f16*)(ws + 25165824);   // 8 MB: [32][2048][64]
    f16* Vtg   = (f16*)(ws + 33554432);   // 8 MB: [32][64][2048] (V transposed)
    f16* valh  = (f16*)(ws + 41943040);   // 8 MB: [4096][1024]

    cvt_f32_f16<<<4096, 256, 0, stream>>>(x, xh, M_TOTAL * D_MODEL / 4);
    transpose_cvt<<<dim3(96, 32), dim3(32, 8), 0, stream>>>(Wqkv, WqkvT, 1024, 3072);
    transpose_cvt<<<dim3(32, 32), dim3(32, 8), 0, stream>>>(Wout, WoutT, 1024, 1024);
    gemm_mfma<0, 128><<<dim3(24, 32), 256, 0, stream>>>(xh, WqkvT, bqkv, Qh, Kh, Vtg, nullptr, 1024);
    l2scale_cvt<<<4096, 256, 0, stream>>>(mask, E, SEQ * SEQ / 4);   // xh dead now
    attn<<<dim3(16, 32), 512, 0, stream>>>(Qh, Kh, Vtg, E, valh);
    gemm_mfma<1, 64><<<dim3(16, 32), 256, 0, stream>>>(valh, WoutT, bout, nullptr, nullptr, nullptr, out, 1024);
}

// Round 9
// 216.867 us; speedup vs baseline: 1.4672x; 1.0279x over previous
//
#include <hip/hip_runtime.h>
#include <hip/hip_bf16.h>

#define D_MODEL 1024
#define NH 16
#define HD 64
#define BATCH 2
#define SEQ 2048
#define M_TOTAL (BATCH*SEQ)   // 4096

typedef _Float16 f16;
typedef _Float16 half8 __attribute__((ext_vector_type(8)));
typedef _Float16 half4v __attribute__((ext_vector_type(4)));
typedef float floatx4 __attribute__((ext_vector_type(4)));

#if __has_builtin(__builtin_amdgcn_exp2f)
#define EXP2(x) __builtin_amdgcn_exp2f(x)
#else
#define EXP2(x) __expf(0.6931471805599453f * (x))
#endif

__device__ inline void gload_lds16(const void* g, void* l) {
    __builtin_amdgcn_global_load_lds(
        (const __attribute__((address_space(1))) unsigned int*)g,
        (__attribute__((address_space(3))) unsigned int*)l, 16, 0, 0);
}

// ---------------- fused prep: x fp32->fp16 cast + both weight transposes ----------------
// One launch replaces three. Branch is uniform per block (blockIdx-based), so the
// __syncthreads inside the transpose body is safe.
__device__ void trans_body(const float* __restrict__ src, f16* __restrict__ dst,
                           int R, int C, int bx, int by) {
    __shared__ float tile[32][33];
    int tx = threadIdx.x & 31;
    int ty = threadIdx.x >> 5;        // 0..7
    int c0 = bx * 32;
    int r0 = by * 32;
    for (int yy = 0; yy < 32; yy += 8)
        tile[ty + yy][tx] = src[(long)(r0 + ty + yy) * C + c0 + tx];
    __syncthreads();
    for (int yy = 0; yy < 32; yy += 8)
        dst[(long)(c0 + ty + yy) * R + r0 + tx] = (f16)tile[tx][ty + yy];
}

__global__ __launch_bounds__(256) void prep(
    const float* __restrict__ x, f16* __restrict__ xh,
    const float* __restrict__ Wqkv, f16* __restrict__ WqkvT,
    const float* __restrict__ Wout, f16* __restrict__ WoutT)
{
    int bid = blockIdx.x;
    if (bid < 1024) {
        // x cast: 1,048,576 float4s, grid-stride x4
        int i = bid * 256 + threadIdx.x;
        #pragma unroll
        for (int it = 0; it < 4; ++it, i += 262144) {
            float4 v = ((const float4*)x)[i];
            half4v o = { (f16)v.x, (f16)v.y, (f16)v.z, (f16)v.w };
            *(half4v*)(xh + (long)i * 4) = o;
        }
    } else if (bid < 1024 + 3072) {
        int t = bid - 1024;                    // Wqkv [1024][3072] -> WqkvT
        trans_body(Wqkv, WqkvT, 1024, 3072, t % 96, t / 96);
    } else {
        int t = bid - 4096;                    // Wout [1024][1024] -> WoutT
        trans_body(Wout, WoutT, 1024, 1024, t % 32, t / 32);
    }
}

// ---------------- m2 = mask * log2(e) in f16 (additive log2-domain mask) ----------------
__global__ void l2scale_cvt(const float* __restrict__ src, f16* __restrict__ dst, int n4) {
    int i = blockIdx.x * blockDim.x + threadIdx.x;
    if (i < n4) {
        float4 v = ((const float4*)src)[i];
        const float L2E = 1.44269504f;
        half4v o = { (f16)(v.x * L2E), (f16)(v.y * L2E), (f16)(v.z * L2E), (f16)(v.w * L2E) };
        *(half4v*)(dst + (long)i * 4) = o;
    }
}

// ---------------- 128xTN-tile fp16 MFMA GEMM, BK=64, XOR-swizzled LDS ----------------
// R1/R8-verified: single-buffered, linear block mapping (50us @ 61% MfmaUtil).
// MODE 0 (TN=128): scatter -> Qh [bh][s][d] (x0.125*log2e), Kh [bh][s][d], Vtg [bh][d][s]
// MODE 1 (TN=64):  out[m][n] = acc + bias (fp32)
template<int MODE, int TN>
__global__ __launch_bounds__(256) void gemm_mfma(
    const f16* __restrict__ A, const f16* __restrict__ BT,
    const float* __restrict__ bias,
    f16* __restrict__ Qh, f16* __restrict__ Kh, f16* __restrict__ Vtg,
    float* __restrict__ out, int Kdim)
{
    constexpr int NF = TN / 32;          // n-frags per wave
    __shared__ f16 Ah[128 * 64];
    __shared__ f16 Bh[TN * 64];
    int tid  = threadIdx.x;
    int wid  = tid >> 6;
    int lane = tid & 63;
    int quad = lane >> 4;
    int l16  = lane & 15;
    int m0 = blockIdx.y * 128;
    int n0 = blockIdx.x * TN;
    int mrow = (wid >> 1) * 64;
    int ncol = (wid & 1) * (TN / 2);
    int grow = lane >> 3;                 // 0..7
    int gchunk = (lane & 7) ^ (grow & 7); // swizzled source chunk
    int sw0 = ((quad)     ^ (l16 & 7)) * 8;   // k-half 0
    int sw1 = ((quad + 4) ^ (l16 & 7)) * 8;   // k-half 1

    floatx4 acc[4][NF];
    #pragma unroll
    for (int mb = 0; mb < 4; mb++)
        #pragma unroll
        for (int nb = 0; nb < NF; nb++) acc[mb][nb] = (floatx4){0.f, 0.f, 0.f, 0.f};

    const f16* Abase = A + (long)m0 * Kdim;
    const f16* Bbase = BT + (long)n0 * Kdim;

    for (int k0 = 0; k0 < Kdim; k0 += 64) {
        #pragma unroll
        for (int j = 0; j < 4; j++) {
            int r = j * 32 + wid * 8 + grow;
            gload_lds16(Abase + (long)r * Kdim + k0 + gchunk * 8, &Ah[(j * 32 + wid * 8) * 64]);
        }
        #pragma unroll
        for (int j = 0; j < TN / 32; j++) {
            int r = j * 32 + wid * 8 + grow;
            gload_lds16(Bbase + (long)r * Kdim + k0 + gchunk * 8, &Bh[(j * 32 + wid * 8) * 64]);
        }
        __syncthreads();
        #pragma unroll
        for (int h = 0; h < 2; h++) {
            int sw = h ? sw1 : sw0;
            half8 af[4];
            #pragma unroll
            for (int mb = 0; mb < 4; mb++)
                af[mb] = *(const half8*)&Ah[(mrow + mb * 16 + l16) * 64 + sw];
            #pragma unroll
            for (int nb = 0; nb < NF; nb++) {
                half8 bf = *(const half8*)&Bh[(ncol + nb * 16 + l16) * 64 + sw];
                #pragma unroll
                for (int mb = 0; mb < 4; mb++)
                    acc[mb][nb] = __builtin_amdgcn_mfma_f32_16x16x32_f16(af[mb], bf, acc[mb][nb], 0, 0, 0);
            }
        }
        __syncthreads();
    }

    #pragma unroll
    for (int nb = 0; nb < NF; nb++) {
        int n = n0 + ncol + nb * 16 + l16;
        float bv = bias[n];
        int head = 0, t = 0, d = 0;
        if (MODE == 0) { head = n / 192; int rem = n % 192; t = rem / 64; d = rem % 64; }
        #pragma unroll
        for (int mb = 0; mb < 4; mb++) {
            int mbase = m0 + mrow + mb * 16 + quad * 4;
            if (MODE == 0) {
                int b = mbase >> 11;
                int s = mbase & 2047;
                long bh = b * NH + head;
                if (t == 2) {
                    half4v pack;
                    #pragma unroll
                    for (int r = 0; r < 4; r++) pack[r] = (f16)(acc[mb][nb][r] + bv);
                    *(half4v*)&Vtg[(bh * HD + d) * SEQ + s] = pack;
                } else if (t == 0) {
                    // 0.125 (1/sqrt(64)) * log2(e): QK^T lands directly in log2 domain
                    #pragma unroll
                    for (int r = 0; r < 4; r++)
                        Qh[(bh * SEQ + s + r) * HD + d] = (f16)((acc[mb][nb][r] + bv) * 0.18033688f);
                } else {
                    #pragma unroll
                    for (int r = 0; r < 4; r++)
                        Kh[(bh * SEQ + s + r) * HD + d] = (f16)(acc[mb][nb][r] + bv);
                }
            } else {
                #pragma unroll
                for (int r = 0; r < 4; r++)
                    out[(long)(mbase + r) * D_MODEL + n] = acc[mb][nb][r] + bv;
            }
        }
    }
}

// ---------------- flash attention (R5 v4, best measured 66.4us): ---------------------
// 8 waves x 16 q-rows, K/V double-buffer + ONE barrier per k-tile, register-E
// ping-pong prefetch, XCD-clustered remap, log2-domain softmax, ones-MFMA denoms.
__global__ __launch_bounds__(512) void attn(
    const f16* __restrict__ Qh, const f16* __restrict__ Kh, const f16* __restrict__ Vtg,
    const f16* __restrict__ E, f16* __restrict__ valh)
{
    __shared__ f16 Kl[2][64 * 64];   // [buf][key][d], swizzled chunks
    __shared__ f16 Vt[2][64 * 64];   // [buf][d][key], swizzled chunks
    __shared__ f16 Pl[8][16 * 68];   // per-wave P [q][key], stride 68 (write-conflict-free)
    int tid  = threadIdx.x;
    int wid  = tid >> 6;             // 0..7
    int lane = tid & 63;
    int quad = lane >> 4;
    int l16  = lane & 15;

    // XCD-clustered bijective remap: each XCD sees 8 bh x 8 q-panels -> L2-resident K/V+E
    int id   = blockIdx.y * 16 + blockIdx.x;
    int xcd  = id & 7;
    int slot = id >> 3;
    int bh   = ((xcd & 3) << 3) | (slot >> 3);
    int qx   = ((xcd >> 2) << 3) | (slot & 7);
    int b  = bh >> 4;
    int h  = bh & 15;
    int qblk = qx * 128;
    int q0 = qblk + wid * 16;

    int wrow = wid * 8 + (lane >> 3);         // 0..63
    int kchunk = (lane & 7) ^ (wrow & 7);
    int sw0 = ((quad)     ^ (l16 & 7)) * 8;   // k-half 0
    int sw1 = ((quad + 4) ^ (l16 & 7)) * 8;   // k-half 1

    const f16* Qbase = Qh + ((long)bh * SEQ + q0) * HD;
    half8 qf[2];
    #pragma unroll
    for (int c = 0; c < 2; c++)
        qf[c] = *(const half8*)&Qbase[(long)l16 * HD + c * 32 + quad * 8];

    half8 onesv;
    #pragma unroll
    for (int j = 0; j < 8; j++) onesv[j] = (f16)1.0f;

    floatx4 Of[4];
    floatx4 ssum = (floatx4){0.f, 0.f, 0.f, 0.f};
    #pragma unroll
    for (int nb = 0; nb < 4; nb++) Of[nb] = (floatx4){0.f, 0.f, 0.f, 0.f};

    const f16* Kb = Kh + (long)bh * SEQ * HD;
    const f16* Vb = Vtg + (long)bh * HD * SEQ;
    const f16* Eb = E + (long)qblk * SEQ;

    auto stage = [&](int buf, int k0) {
        gload_lds16(Kb + (long)(k0 + wrow) * HD + kchunk * 8, &Kl[buf][(wid * 8) * 64]);
        gload_lds16(Vb + (long)wrow * SEQ + k0 + kchunk * 8, &Vt[buf][(wid * 8) * 64]);
    };

    stage(0, 0);
    __syncthreads();                  // vmcnt(0) drain: buf0 ready

    auto iter = [&](const int buf, int k0) {
        bool notlast = (k0 + 64 < SEQ);
        if (notlast) stage(buf ^ 1, k0 + 64);   // DMA flies under this iter's compute

        // m2 loads for THIS iter: issue before QK so L2 latency hides under MFMAs
        f16 ef[4][4];
        #pragma unroll
        for (int r = 0; r < 4; r++) {
            const f16* Erow = Eb + (long)(wid * 16 + quad * 4 + r) * SEQ + k0 + l16;
            #pragma unroll
            for (int kb = 0; kb < 4; kb++) ef[r][kb] = Erow[kb * 16];
        }

        // QK^T: 16 q-rows x 64 keys (result already in log2 domain)
        floatx4 sc[4];
        __builtin_amdgcn_s_setprio(1);
        #pragma unroll
        for (int kb = 0; kb < 4; kb++) {
            half8 kf0 = *(const half8*)&Kl[buf][(kb * 16 + l16) * 64 + sw0];
            half8 kf1 = *(const half8*)&Kl[buf][(kb * 16 + l16) * 64 + sw1];
            floatx4 s = (floatx4){0.f, 0.f, 0.f, 0.f};
            s = __builtin_amdgcn_mfma_f32_16x16x32_f16(qf[0], kf0, s, 0, 0, 0);
            s = __builtin_amdgcn_mfma_f32_16x16x32_f16(qf[1], kf1, s, 0, 0, 0);
            sc[kb] = s;
        }
        __builtin_amdgcn_s_setprio(0);

        // p = exp2(s + m2)
        #pragma unroll
        for (int kb = 0; kb < 4; kb++)
            #pragma unroll
            for (int r = 0; r < 4; r++) {
                float p = EXP2(sc[kb][r] + (float)ef[r][kb]);
                Pl[wid][(quad * 4 + r) * 68 + kb * 16 + l16] = (f16)p;
            }

        // wave-private LDS round-trip (C-layout -> A-layout); no barrier needed
        half8 pf0 = *(const half8*)&Pl[wid][l16 * 68 + quad * 8];
        half8 pf1 = *(const half8*)&Pl[wid][l16 * 68 + 32 + quad * 8];

        __builtin_amdgcn_s_setprio(1);
        // denominators: ssum[q] += sum_key P[q][key] via ones-B MFMA
        ssum = __builtin_amdgcn_mfma_f32_16x16x32_f16(pf0, onesv, ssum, 0, 0, 0);
        ssum = __builtin_amdgcn_mfma_f32_16x16x32_f16(pf1, onesv, ssum, 0, 0, 0);
        #pragma unroll
        for (int nb = 0; nb < 4; nb++) {
            half8 vf0 = *(const half8*)&Vt[buf][(nb * 16 + l16) * 64 + sw0];
            half8 vf1 = *(const half8*)&Vt[buf][(nb * 16 + l16) * 64 + sw1];
            Of[nb] = __builtin_amdgcn_mfma_f32_16x16x32_f16(pf0, vf0, Of[nb], 0, 0, 0);
            Of[nb] = __builtin_amdgcn_mfma_f32_16x16x32_f16(pf1, vf1, Of[nb], 0, 0, 0);
        }
        __builtin_amdgcn_s_setprio(0);

        __syncthreads();  // drains stage(buf^1); proves all reads of buf done
    };

    for (int k0 = 0; k0 < SEQ; k0 += 128) {
        iter(0, k0);
        iter(1, k0 + 64);
    }

    float rinv[4];
    #pragma unroll
    for (int r = 0; r < 4; r++) rinv[r] = 1.f / ssum[r];

    #pragma unroll
    for (int nb = 0; nb < 4; nb++)
        #pragma unroll
        for (int r = 0; r < 4; r++) {
            int q = q0 + quad * 4 + r;
            int d = nb * 16 + l16;
            valh[((long)(b * SEQ + q)) * D_MODEL + h * HD + d] = (f16)(Of[nb][r] * rinv[r]);
        }
}

extern "C" void kernel_launch(void* const* d_in, const int* in_sizes, int n_in,
                              void* d_out, int out_size, void* d_ws, size_t ws_size,
                              hipStream_t stream) {
    const float* x    = (const float*)d_in[0];
    const float* mask = (const float*)d_in[1];
    const float* Wqkv = (const float*)d_in[2];
    const float* bqkv = (const float*)d_in[3];
    const float* Wout = (const float*)d_in[4];
    const float* bout = (const float*)d_in[5];
    float* out = (float*)d_out;

    char* ws = (char*)d_ws;
    f16* xh    = (f16*)(ws + 0);          // 8 MB: [4096][1024]; dead after gemm0
    f16* E     = (f16*)(ws + 0);          // 8 MB: [2048][2048] mask*log2e — overlays xh
    f16* WqkvT = (f16*)(ws + 8388608);    // 6 MB: [3072][1024]
    f16* WoutT = (f16*)(ws + 14680064);   // 2 MB: [1024][1024]
    f16* Qh    = (f16*)(ws + 16777216);   // 8 MB: [32][2048][64] (pre-scaled 0.125*log2e)
    f16* Kh    = (f16*)(ws + 25165824);   // 8 MB: [32][2048][64]
    f16* Vtg   = (f16*)(ws + 33554432);   // 8 MB: [32][64][2048] (V transposed)
    f16* valh  = (f16*)(ws + 41943040);   // 8 MB: [4096][1024]

    prep<<<5120, 256, 0, stream>>>(x, xh, Wqkv, WqkvT, Wout, WoutT);
    gemm_mfma<0, 128><<<dim3(24, 32), 256, 0, stream>>>(xh, WqkvT, bqkv, Qh, Kh, Vtg, nullptr, 1024);
    l2scale_cvt<<<4096, 256, 0, stream>>>(mask, E, SEQ * SEQ / 4);   // xh dead now
    attn<<<dim3(16, 32), 512, 0, stream>>>(Qh, Kh, Vtg, E, valh);
    gemm_mfma<1, 64><<<dim3(16, 32), 256, 0, stream>>>(valh, WoutT, bout, nullptr, nullptr, nullptr, out, 1024);
}